// Round 11
// baseline (141.799 us; speedup 1.0000x reference)
//
#include <hip/hip_runtime.h>
#include <hip/hip_bf16.h>
#include <cstdint>
#include <cstddef>
#include <math.h>

#define D 256
#define TEMP_INV 2.0f       // 1 / TEMPERATURE, TEMPERATURE = 0.5
#define EPS_NORM 1e-8f
#define NTILES 2080         // 64*65/2 upper-triangular 128x128 tiles

typedef __attribute__((ext_vector_type(8))) short bf16x8;
typedef __attribute__((ext_vector_type(4))) float f32x4;

// ---------------- kernel 1: normalize rows, write bf16 zn ----------------
// 512 blocks x 4 waves, grid-stride over 8192 rows (4 rows/wave).
__global__ void __launch_bounds__(256) normalize_rows(
    const float* __restrict__ zi, const float* __restrict__ zj,
    __hip_bfloat16* __restrict__ zn, float* __restrict__ out, int B) {
  const int wid = threadIdx.x >> 6;
  const int lane = threadIdx.x & 63;
  if (blockIdx.x == 0 && threadIdx.x == 0) out[0] = 0.0f;  // finalize atomic dst
#pragma unroll
  for (int it = 0; it < 4; ++it) {
    int row = it * 2048 + blockIdx.x * 4 + wid;
    const float* src = (row < B) ? (zi + (size_t)row * D)
                                 : (zj + (size_t)(row - B) * D);
    float4 v = ((const float4*)src)[lane];
    float ss = v.x * v.x + v.y * v.y + v.z * v.z + v.w * v.w;
    for (int off = 32; off; off >>= 1) ss += __shfl_xor(ss, off);
    float rn = 1.0f / fmaxf(sqrtf(ss), EPS_NORM);
    union { ushort4 u; __hip_bfloat16 h[4]; } o;
    o.h[0] = __float2bfloat16(v.x * rn);
    o.h[1] = __float2bfloat16(v.y * rn);
    o.h[2] = __float2bfloat16(v.z * rn);
    o.h[3] = __float2bfloat16(v.w * rn);
    ((ushort4*)zn)[(size_t)row * (D / 4) + lane] = o.u;
  }
}

// ---------------- kernel 2: fused sim GEMM + exp + masked row/col sums ---
// R18: WAVE-INDEPENDENT GEMM — zero LDS, zero barriers.
// Diagnosis at R13's 37us: per-CU time/tile 10.9k cy vs pipe models
// DS 4.6k + VALU 2.3k + MFMA 1.45k = 77% SERIAL sum -> the 2-barrier
// cadence phase-locks all waves (blocks co-start), so DS/MFMA/VALU phases
// never overlap across the CU (m114: overlap needs phase-diverse waves).
// Fix: each wave owns a 64x64 quadrant of the 128x128 tile and loads BOTH
// MFMA operand fragments STRAIGHT FROM GLOBAL (pattern verified correct in
// R17 for A; B is the identical pattern on bn rows):
//   frag[x] = zn[(base + x*16 + frow)*D + kc*32 + quad*8]   (16B/lane)
// 8 K-chunks x {8 frag loads + 16 MFMA}, no ds_write/ds_read, no
// __syncthreads anywhere -> 16 independent wave-pipelines per CU drift
// into different phases; TA/L2 latency of one wave hides under others'
// MFMAs. L2 panel traffic doubles (no LDS dedup: 532 MB total, L2-BW
// floor ~6-15us) — accepted to buy phase diversity.
// Epilogue wave-local too: row-sums shfl over colq lanes, col-sums over
// quad lanes; part gets QUADRANT slots [2*Nb][N] (each written exactly
// once; atomic-free). Diag mask only in diag-quadrants (isDiag && wy==wx);
// positives live in quadrants (wy==wx) of bx==by+B/128 blocks.
// Reg audit (R15/R16 lesson): acc 64 + a/b 32 + 8 row-addrs 16 + misc
// ~10 = ~122 <= 128 cap at (256,4). Tripwire: VGPR<=64 or WRITE>>5MB.
__device__ __forceinline__ void decode_tile(int t, int Nb, int& by, int& bx) {
  float fb = (2.0f * Nb + 1.0f -
              sqrtf((float)((2 * Nb + 1) * (2 * Nb + 1) - 8 * t))) * 0.5f;
  int y = (int)fb;
  while ((y + 1) * Nb - ((y + 1) * y) / 2 <= t) ++y;
  while (y * Nb - (y * (y - 1)) / 2 > t) --y;
  by = y;
  bx = y + (t - (y * Nb - (y * (y - 1)) / 2));
}

__global__ void __launch_bounds__(256, 4) ntxent_gemm(
    const __hip_bfloat16* __restrict__ zn,
    float* __restrict__ part, float* __restrict__ pos, int B) {
  const int N = 2 * B;
  const int Nb = N / 128;  // 64
  int by, bx;
  decode_tile(blockIdx.x, Nb, by, bx);
  const int bm = by * 128;
  const int bn = bx * 128;

  const int tid = threadIdx.x;
  const int wid = tid >> 6;
  const int lane = tid & 63;
  const int wy = wid >> 1, wx = wid & 1;

  const int frow = lane & 15;   // fragment row within 16-row group == colq
  const int quad = lane >> 4;   // 16B column chunk selector / C row group

  // quadrant-level predicates (wave-uniform)
  const bool diagQ = (by == bx) && (wy == wx);            // self-mask needed
  const bool posQ = (bx == by + B / 128) && (wy == wx);   // holds positives
  const bool isDiag = (by == bx);                         // no col-sum slots

  // global fragment bases: row (bm|bn) + (wy|wx)*64 + x*16 + frow, col quad*8
  const __hip_bfloat16* gA = zn + (size_t)(bm + wy * 64 + frow) * D + quad * 8;
  const __hip_bfloat16* gB = zn + (size_t)(bn + wx * 64 + frow) * D + quad * 8;

  f32x4 acc[4][4] = {};

#pragma unroll
  for (int kc = 0; kc < 8; ++kc) {
    const int kcol = kc * 32;
    bf16x8 a[4], b[4];
#pragma unroll
    for (int i = 0; i < 4; ++i)
      a[i] = *(const bf16x8*)(gA + (size_t)(i * 16) * D + kcol);
#pragma unroll
    for (int j = 0; j < 4; ++j)
      b[j] = *(const bf16x8*)(gB + (size_t)(j * 16) * D + kcol);
#pragma unroll
    for (int i = 0; i < 4; ++i)
#pragma unroll
      for (int j = 0; j < 4; ++j)
        acc[i][j] =
            __builtin_amdgcn_mfma_f32_16x16x32_bf16(a[i], b[j], acc[i][j], 0, 0, 0);
  }

  // ---- epilogue (fully wave-local). C/D: col = lane&15, row = quad*4+reg.
  const int colq = frow;
  float cs[4] = {0.0f, 0.0f, 0.0f, 0.0f};
#pragma unroll
  for (int i = 0; i < 4; ++i) {
#pragma unroll
    for (int r = 0; r < 4; ++r) {
      int rowoff = i * 16 + quad * 4 + r;        // 0..63 within quadrant
      int row = bm + wy * 64 + rowoff;
      float rs = 0.0f;
#pragma unroll
      for (int j = 0; j < 4; ++j) {
        int coloff = j * 16 + colq;              // 0..63 within quadrant
        float v = acc[i][j][r];
        float e = __expf(v * TEMP_INV);
        e = (diagQ && coloff == rowoff) ? 0.0f : e;
        rs += e;
        cs[j] += e;
        if (posQ && coloff == rowoff) { pos[row] = v; pos[row + B] = v; }
      }
      // sum across colq (lane bits 0..3) -> full 64-col row sum
      rs += __shfl_xor(rs, 1);
      rs += __shfl_xor(rs, 2);
      rs += __shfl_xor(rs, 4);
      rs += __shfl_xor(rs, 8);
      if (colq == 0) part[(size_t)(2 * bx + wx) * N + row] = rs;
    }
  }
  if (!isDiag) {
    // sum across quad (lane bits 4..5) -> full 64-row col sum
#pragma unroll
    for (int j = 0; j < 4; ++j) {
      float c = cs[j];
      c += __shfl_xor(c, 16);
      c += __shfl_xor(c, 32);
      if (quad == 0)
        part[(size_t)(2 * by + wy) * N + bn + wx * 64 + j * 16 + colq] = c;
    }
  }
}

// ---------------- kernel 3: reduce partials + finalize loss scalar -------
// 32 blocks x 256 threads; thread owns one global row idx. 128 slots now.
__global__ void __launch_bounds__(256) finalize(
    const float* __restrict__ part, const float* __restrict__ pos,
    float* __restrict__ out, int N) {
  const int idx = blockIdx.x * 256 + threadIdx.x;
  const int NS = N / 64;  // 128 quadrant slots
  float s = 0.0f;
#pragma unroll 16
  for (int k = 0; k < NS; ++k) s += part[(size_t)k * N + idx];
  float loss = __logf(s) - pos[idx] * TEMP_INV;
  for (int off = 32; off; off >>= 1) loss += __shfl_xor(loss, off);
  __shared__ float redsh[4];
  if ((threadIdx.x & 63) == 0) redsh[threadIdx.x >> 6] = loss;
  __syncthreads();
  if (threadIdx.x == 0) {
    float tt = redsh[0] + redsh[1] + redsh[2] + redsh[3];
    atomicAdd(out, tt / (float)N);
  }
}

extern "C" void kernel_launch(void* const* d_in, const int* in_sizes, int n_in,
                              void* d_out, int out_size, void* d_ws, size_t ws_size,
                              hipStream_t stream) {
  const float* zi = (const float*)d_in[0];
  const float* zj = (const float*)d_in[1];
  const int B = in_sizes[0] / D;  // 4096
  const int N = 2 * B;            // 8192

  __hip_bfloat16* zn = (__hip_bfloat16*)d_ws;
  float* pos = (float*)((char*)d_ws + (size_t)N * D * sizeof(__hip_bfloat16));
  float* part = pos + N;          // [N/64][N] floats = 4 MB

  normalize_rows<<<512, 256, 0, stream>>>(zi, zj, zn, (float*)d_out, B);
  ntxent_gemm<<<NTILES, 256, 0, stream>>>(zn, part, pos, B);
  finalize<<<N / 256, 256, 0, stream>>>(part, pos, (float*)d_out, N);
}